// Round 7
// baseline (60.422 us; speedup 1.0000x reference)
//
#include <hip/hip_runtime.h>
#include <hip/hip_fp16.h>

#define NATOM 8192
#define FR    128
#define NSEG  64
#define PPB   512     // pair-kernel blocks
#define PTH   512     // pair-kernel threads
#define PPT   16      // pairs per thread

typedef _Float16 v8h __attribute__((ext_vector_type(8)));
typedef _Float16 v4h __attribute__((ext_vector_type(4)));
typedef float    v4f __attribute__((ext_vector_type(4)));

__device__ __forceinline__ float fast_tanh(float x)
{
    float t = __expf(2.f * x);
    return 1.f - 2.f * __builtin_amdgcn_rcpf(t + 1.f);
}

// ---------------- kernel 0: f16 hi/lo split + transposed weight planes ----------------
// planes (f16 units): [0)=W1Th[256 c][128 k], [32768)=W1Tl (x4096),
// [65536)=W2Th[128 c][128 k], [81920)=W2Tl (x4096). c-ranges: sigma||eps.
__global__ __launch_bounds__(512) void k_prep(
    const float* __restrict__ w1s, const float* __restrict__ w1e,
    const float* __restrict__ w2s, const float* __restrict__ w2e,
    _Float16* __restrict__ planes)
{
    int i = blockIdx.x * 512 + threadIdx.x;
    if (i < 32768) {
        int c = i >> 7, k = i & 127;
        float x = (c < 128) ? w1s[k * 128 + c] : w1e[k * 128 + (c - 128)];
        _Float16 h = (_Float16)x;
        planes[i] = h;
        planes[32768 + i] = (_Float16)((x - (float)h) * 4096.f);
    } else if (i < 49152) {
        int u = i - 32768;
        int c = u >> 7, k = u & 127;
        float x = (c < 64) ? w2s[k * 64 + c] : w2e[k * 64 + (c - 64)];
        _Float16 h = (_Float16)x;
        planes[65536 + u] = h;
        planes[81920 + u] = (_Float16)((x - (float)h) * 4096.f);
    }
}

// ---------------- kernel 1: MFMA MLP (split-f16, ~f32 accurate) ----------------
// 128 blocks x 512 thr (8 waves), 64 atoms/block. Wave: at = wv&3 (16-atom tile),
// chf = wv>>2 (col half / path). GEMM1: A=W1T (M=256 cols), B=r (N=atoms),
// D[col][atom]; 3 passes: hi*hi into acc, hi*lo + lo*hi (x4096) into corr.
// h1 -> swizzled LDS f16 hi/lo; GEMM2 same pattern with A=W2T, B=h1.
// K-mapping used identically for A and B frags (any consistent permutation is
// dot-invariant); C/D layout is the m89-verified col=lane&15, row=(l>>4)*4+reg.
__global__ __launch_bounds__(512) void k_mm(
    const float* __restrict__ r, const float* __restrict__ xyz,
    const _Float16* __restrict__ planes,
    const float* __restrict__ b1s, const float* __restrict__ b1e,
    const float* __restrict__ b2s, const float* __restrict__ b2e,
    const float* __restrict__ w3s, const float* __restrict__ w3e,
    const float* __restrict__ b3s, const float* __restrict__ b3e,
    float4* __restrict__ atomd)
{
    extern __shared__ char ldsraw[];
    _Float16* Wh  = (_Float16*)ldsraw;           // phase1: [256][128] swizzled
    _Float16* Wl  = Wh + 32768;
    _Float16* h1h = Wh;                          // phase2: [64][256] swizzled
    _Float16* h1l = Wh + 16384;
    _Float16* W2h = Wh + 32768;                  // [128][128] swizzled
    _Float16* W2l = Wh + 49152;
    float*    mArr = (float*)(ldsraw + 131072);  // [128]

    const int tid = threadIdx.x;
    const int a0  = blockIdx.x * 64;
    const int l = tid & 63, wv = tid >> 6;
    const int row16 = l & 15, kgrp = l >> 4;
    const int at = wv & 3, chf = wv >> 2;

    // ---- stage W1T (both planes) swizzled: chunk' = chunk ^ (c&15) ----
    {
        const uint4* ph = (const uint4*)planes;
        const uint4* pl = (const uint4*)(planes + 32768);
        uint4* dh = (uint4*)Wh; uint4* dl = (uint4*)Wl;
#pragma unroll
        for (int i = 0; i < 8; ++i) {
            int g = i * 512 + tid;
            int c = g >> 4, ch = g & 15;
            int sw = c * 16 + (ch ^ (c & 15));
            dh[sw] = ph[g]; dl[sw] = pl[g];
        }
    }

    // ---- r fragments (global, inline hi/lo split), k = ks*32 + kgrp*8 + j ----
    v8h rh[4], rl[4];
    {
        const float* rb = r + (size_t)(a0 + at * 16 + row16) * FR + kgrp * 8;
#pragma unroll
        for (int ks = 0; ks < 4; ++ks) {
            float4 x0 = *(const float4*)(rb + ks * 32);
            float4 x1 = *(const float4*)(rb + ks * 32 + 4);
            float xs[8] = {x0.x, x0.y, x0.z, x0.w, x1.x, x1.y, x1.z, x1.w};
#pragma unroll
            for (int j = 0; j < 8; ++j) {
                _Float16 h = (_Float16)xs[j];
                rh[ks][j] = h;
                rl[ks][j] = (_Float16)((xs[j] - (float)h) * 4096.f);
            }
        }
    }
    __syncthreads();

    // ---- GEMM1: wave covers cols [chf*128, +128), atoms [at*16, +16) ----
    v4h hpack[8], lpack[8];
    {
#pragma unroll
        for (int ct = 0; ct < 8; ++ct) {
            int crow = chf * 128 + ct * 16 + row16;       // A-frag row (weight col)
            v4f a = {0.f, 0.f, 0.f, 0.f}, cr = {0.f, 0.f, 0.f, 0.f};
            int rbo = crow * 128, sw = crow & 15;
#pragma unroll
            for (int ks = 0; ks < 4; ++ks) {
                int off = rbo + (((ks * 4 + kgrp) ^ sw) * 8);
                v8h wh = *(const v8h*)(Wh + off);
                v8h wl = *(const v8h*)(Wl + off);
                a  = __builtin_amdgcn_mfma_f32_16x16x32_f16(wh, rh[ks], a,  0, 0, 0);
                cr = __builtin_amdgcn_mfma_f32_16x16x32_f16(wh, rl[ks], cr, 0, 0, 0);
                cr = __builtin_amdgcn_mfma_f32_16x16x32_f16(wl, rh[ks], cr, 0, 0, 0);
            }
            int colb = chf * 128 + ct * 16 + kgrp * 4;    // this lane's D rows
            const float* bp = (colb < 128) ? (b1s + colb) : (b1e + (colb - 128));
            float4 bv = *(const float4*)bp;
            float bvx[4] = {bv.x, bv.y, bv.z, bv.w};
#pragma unroll
            for (int j = 0; j < 4; ++j) {
                float v = fast_tanh(a[j] + cr[j] * 2.44140625e-4f + bvx[j]);
                _Float16 h = (_Float16)v;
                hpack[ct][j] = h;
                lpack[ct][j] = (_Float16)((v - (float)h) * 4096.f);
            }
        }
    }
    __syncthreads();   // all W1T reads done; LDS reused below

    // ---- write h1 (swizzled: chunk' = chunk ^ (atom&15)) + stage W2T ----
    {
        int arow = at * 16 + row16;
#pragma unroll
        for (int ct = 0; ct < 8; ++ct) {
            int colb = chf * 128 + ct * 16 + kgrp * 4;
            int chs = (colb >> 3) ^ row16;
            int off = arow * 256 + chs * 8 + (colb & 7);
            *(v4h*)(h1h + off) = hpack[ct];
            *(v4h*)(h1l + off) = lpack[ct];
        }
        const uint4* ph = (const uint4*)(planes + 65536);
        const uint4* pl = (const uint4*)(planes + 81920);
        uint4* dh = (uint4*)W2h; uint4* dl = (uint4*)W2l;
#pragma unroll
        for (int i = 0; i < 4; ++i) {
            int g = i * 512 + tid;
            int c = g >> 4, ch = g & 15;
            int sw = c * 16 + (ch ^ (c & 15));
            dh[sw] = ph[g]; dl[sw] = pl[g];
        }
    }
    __syncthreads();

    // ---- GEMM2 (path = chf) + layer 3 ----
    {
        const int arow = at * 16 + row16;
        v8h bh[4], bl[4];
#pragma unroll
        for (int ks = 0; ks < 4; ++ks) {
            int chunk = chf * 16 + ks * 4 + kgrp;
            int off = arow * 256 + ((chunk ^ row16) * 8);
            bh[ks] = *(const v8h*)(h1h + off);
            bl[ks] = *(const v8h*)(h1l + off);
        }
        float ps = 0.f;
#pragma unroll
        for (int ct2 = 0; ct2 < 4; ++ct2) {
            int c2 = chf * 64 + ct2 * 16 + row16;
            v4f a = {0.f, 0.f, 0.f, 0.f}, cr = {0.f, 0.f, 0.f, 0.f};
            int rbo = c2 * 128, sw = c2 & 15;
#pragma unroll
            for (int ks = 0; ks < 4; ++ks) {
                int off = rbo + (((ks * 4 + kgrp) ^ sw) * 8);
                v8h wh = *(const v8h*)(W2h + off);
                v8h wl = *(const v8h*)(W2l + off);
                a  = __builtin_amdgcn_mfma_f32_16x16x32_f16(wh, bh[ks], a,  0, 0, 0);
                cr = __builtin_amdgcn_mfma_f32_16x16x32_f16(wh, bl[ks], cr, 0, 0, 0);
                cr = __builtin_amdgcn_mfma_f32_16x16x32_f16(wl, bh[ks], cr, 0, 0, 0);
            }
            int cb = ct2 * 16 + kgrp * 4;                 // col within path [0,64)
            float4 b2v = *(const float4*)((chf ? b2e : b2s) + cb);
            float4 w3v = *(const float4*)((chf ? w3e : w3s) + cb);
            float b2x[4] = {b2v.x, b2v.y, b2v.z, b2v.w};
            float w3x[4] = {w3v.x, w3v.y, w3v.z, w3v.w};
#pragma unroll
            for (int j = 0; j < 4; ++j) {
                float h2 = fast_tanh(a[j] + cr[j] * 2.44140625e-4f + b2x[j]);
                ps = fmaf(h2, w3x[j], ps);
            }
        }
        ps += __shfl_xor(ps, 16);
        ps += __shfl_xor(ps, 32);
        if (l < 16) mArr[chf * 64 + at * 16 + l] = ps + (chf ? b3e[0] : b3s[0]);
    }
    __syncthreads();

    if (tid < 64) {
        int atom = a0 + tid;
        float ms = mArr[tid], me = mArr[64 + tid];
        float sg = fmaf(10.f * ms, ms, 4.f);            // sigma = 4 + 10 m^2
        float p  = sg * sqrtf(sg);                      // sigma^1.5
        float q  = 0.31622776601683794f * fabsf(me);    // sqrt(eps)
        __half2 pq = __halves2half2(__float2half(p), __float2half(q));
        atomd[atom] = make_float4(xyz[3 * atom], xyz[3 * atom + 1],
                                  xyz[3 * atom + 2], __builtin_bit_cast(float, pq));
    }
}

// ---------------- kernel 2: pair energies (global gathers, L2-resident atomd) ----------------
__device__ __forceinline__ float pair_e_g(const float4* __restrict__ atomg, int ia, int ib)
{
    float4 A = atomg[ia], B = atomg[ib];
    float dx = A.x - B.x, dy = A.y - B.y, dz = A.z - B.z;
    float D2 = fmaf(dx, dx, fmaf(dy, dy, dz * dz));
    float inv = __builtin_amdgcn_rcpf(D2);
    float inv3 = inv * inv * inv;
    __half2 ha = __builtin_bit_cast(__half2, A.w);
    __half2 hb = __builtin_bit_cast(__half2, B.w);
    float pp = __low2float(ha) * __low2float(hb);    // (sig_i*sig_j)^1.5
    float qq = __high2float(ha) * __high2float(hb);  // eps_mixed
    float s6 = pp * pp * inv3;                       // (sig_i*sig_j)^3 / D2^3
    return 4.f * qq * (s6 * s6 - s6);
}

__global__ __launch_bounds__(PTH) void k_pair(
    const float4* __restrict__ atomg, const int* __restrict__ pairs,
    const int* __restrict__ num_pairs,
    float* __restrict__ blocksums, int P)
{
    __shared__ int   off[65];
    __shared__ float bsum[64];
    const int tid = threadIdx.x;

    if (tid < 64) {
        int run = num_pairs[tid];
#pragma unroll
        for (int d = 1; d < 64; d <<= 1) {
            int o = __shfl_up(run, d);
            if (tid >= d) run += o;
        }
        off[tid + 1] = run;
        if (tid == 0) off[0] = 0;
        bsum[tid] = 0.f;
    }
    __syncthreads();

    const int base = (blockIdx.x * PTH + tid) * PPT;
    const bool fast = (base + PPT <= P);

    if (__all(fast)) {
        int pr2[PPT * 2];
        const int4* pp4 = (const int4*)(pairs + (size_t)base * 2);
#pragma unroll
        for (int i = 0; i < PPT / 2; ++i) {
            int4 v = pp4[i];
            pr2[4*i] = v.x; pr2[4*i+1] = v.y; pr2[4*i+2] = v.z; pr2[4*i+3] = v.w;
        }
        int s = 0;
#pragma unroll
        for (int st = 32; st; st >>= 1) { int ns = s + st; if (ns <= NSEG - 1 && off[ns] <= base) s = ns; }
        float acc = 0.f;
        if (base + PPT <= off[s + 1] || s == NSEG - 1) {
#pragma unroll
            for (int i = 0; i < PPT; ++i)
                acc += pair_e_g(atomg, pr2[2 * i], pr2[2 * i + 1]);
        } else {
            int off_next = off[s + 1];
#pragma unroll
            for (int i = 0; i < PPT; ++i) {
                int idx = base + i;
                while (s < NSEG - 1 && idx >= off_next) {
                    if (acc != 0.f) atomicAdd(&bsum[s], acc);
                    acc = 0.f; ++s; off_next = off[s + 1];
                }
                acc += pair_e_g(atomg, pr2[2 * i], pr2[2 * i + 1]);
            }
        }
        int s0 = __builtin_amdgcn_readfirstlane(s);
        if (__all(s == s0)) {
            float v = acc;
#pragma unroll
            for (int o = 32; o; o >>= 1) v += __shfl_xor(v, o);
            if ((tid & 63) == 0) atomicAdd(&bsum[s0], v);
        } else {
            atomicAdd(&bsum[s], acc);
        }
    } else if (base < P) {
        int s = 0;
#pragma unroll
        for (int st = 32; st; st >>= 1) { int ns = s + st; if (ns <= NSEG - 1 && off[ns] <= base) s = ns; }
        int off_next = off[s + 1];
        float acc = 0.f;
        for (int i = 0; i < PPT; ++i) {
            int idx = base + i;
            if (idx >= P) break;
            while (s < NSEG - 1 && idx >= off_next) {
                if (acc != 0.f) atomicAdd(&bsum[s], acc);
                acc = 0.f; ++s; off_next = off[s + 1];
            }
            acc += pair_e_g(atomg, pairs[2 * (size_t)idx], pairs[2 * (size_t)idx + 1]);
        }
        if (acc != 0.f) atomicAdd(&bsum[s], acc);
    }
    __syncthreads();
    if (tid < 64) blocksums[blockIdx.x * 64 + tid] = bsum[tid];
}

// ---------------- kernel 3: deterministic final reduce ----------------
__global__ __launch_bounds__(1024) void k_reduce(const float* __restrict__ bs, float* __restrict__ out)
{
    __shared__ float red[16][NSEG];
    int b = threadIdx.x & 63, part = threadIdx.x >> 6;
    float s = 0.f;
    for (int j = part; j < PPB; j += 16) s += bs[(size_t)j * NSEG + b];
    red[part][b] = s;
    __syncthreads();
    if (threadIdx.x < NSEG) {
        float t = 0.f;
#pragma unroll
        for (int p = 0; p < 16; ++p) t += red[p][threadIdx.x];
        out[threadIdx.x] = t;
    }
}

extern "C" void kernel_launch(void* const* d_in, const int* in_sizes, int n_in,
                              void* d_out, int out_size, void* d_ws, size_t ws_size,
                              hipStream_t stream)
{
    const float* r    = (const float*)d_in[0];
    const float* xyz  = (const float*)d_in[1];
    const int*   prs  = (const int*)d_in[2];
    const int*   np   = (const int*)d_in[3];
    const float* sW1  = (const float*)d_in[4];
    const float* sb1  = (const float*)d_in[5];
    const float* sW2  = (const float*)d_in[6];
    const float* sb2  = (const float*)d_in[7];
    const float* sW3  = (const float*)d_in[8];
    const float* sb3  = (const float*)d_in[9];
    const float* eW1  = (const float*)d_in[10];
    const float* eb1  = (const float*)d_in[11];
    const float* eW2  = (const float*)d_in[12];
    const float* eb2  = (const float*)d_in[13];
    const float* eW3  = (const float*)d_in[14];
    const float* eb3  = (const float*)d_in[15];
    float* out = (float*)d_out;
    const int P = in_sizes[2] / 2;

    _Float16* planes = (_Float16*)d_ws;                          // 98304 f16 = 192 KB
    float4*   atomd  = (float4*)((char*)d_ws + 196608);          // 8192 f4 = 128 KB
    float*    bsums  = (float*)((char*)d_ws + 196608 + 131072);  // PPB*64 f32 = 128 KB

    k_prep<<<96, 512, 0, stream>>>(sW1, eW1, sW2, eW2, planes);

    size_t smem1 = 131072 + 512;   // W/h1 regions + mArr
    hipFuncSetAttribute((const void*)k_mm, hipFuncAttributeMaxDynamicSharedMemorySize, (int)smem1);
    k_mm<<<NATOM / 64, 512, smem1, stream>>>(r, xyz, planes, sb1, eb1, sb2, eb2,
                                             sW3, eW3, sb3, eb3, atomd);

    k_pair<<<PPB, PTH, 0, stream>>>(atomd, prs, np, bsums, P);
    k_reduce<<<1, 1024, 0, stream>>>(bsums, out);
}

// Round 8
// 37.918 us; speedup vs baseline: 1.5935x; 1.5935x over previous
//
#include <hip/hip_runtime.h>
#include <hip/hip_fp16.h>

#define NATOM 8192
#define FR    128
#define NSEG  64
#define PB    256     // pair-kernel blocks
#define PT    1024    // pair-kernel threads/block
#define PPT   16      // pairs per thread

typedef _Float16 v8h __attribute__((ext_vector_type(8)));
typedef _Float16 v4h __attribute__((ext_vector_type(4)));
typedef float    v4f __attribute__((ext_vector_type(4)));

__device__ __forceinline__ float fast_tanh(float x)
{
    float t = __expf(2.f * x);
    return 1.f - 2.f * __builtin_amdgcn_rcpf(t + 1.f);
}

// ---------------- kernel 0: f16 hi/lo split + transposed weight planes ----------------
__global__ __launch_bounds__(512) void k_prep(
    const float* __restrict__ w1s, const float* __restrict__ w1e,
    const float* __restrict__ w2s, const float* __restrict__ w2e,
    _Float16* __restrict__ planes)
{
    int i = blockIdx.x * 512 + threadIdx.x;
    if (i < 32768) {
        int c = i >> 7, k = i & 127;
        float x = (c < 128) ? w1s[k * 128 + c] : w1e[k * 128 + (c - 128)];
        _Float16 h = (_Float16)x;
        planes[i] = h;
        planes[32768 + i] = (_Float16)((x - (float)h) * 4096.f);
    } else if (i < 49152) {
        int u = i - 32768;
        int c = u >> 7, k = u & 127;
        float x = (c < 64) ? w2s[k * 64 + c] : w2e[k * 64 + (c - 64)];
        _Float16 h = (_Float16)x;
        planes[65536 + u] = h;
        planes[81920 + u] = (_Float16)((x - (float)h) * 4096.f);
    }
}

// ---------------- kernel 1: MFMA MLP (split-f16, ~f32 accurate) ----------------
// UNCHANGED from round 7 (verified correct). 128 blocks x 512 thr, 64 atoms/blk.
__global__ __launch_bounds__(512) void k_mm(
    const float* __restrict__ r, const float* __restrict__ xyz,
    const _Float16* __restrict__ planes,
    const float* __restrict__ b1s, const float* __restrict__ b1e,
    const float* __restrict__ b2s, const float* __restrict__ b2e,
    const float* __restrict__ w3s, const float* __restrict__ w3e,
    const float* __restrict__ b3s, const float* __restrict__ b3e,
    float4* __restrict__ atomd)
{
    extern __shared__ char ldsraw[];
    _Float16* Wh  = (_Float16*)ldsraw;           // phase1: [256][128] swizzled
    _Float16* Wl  = Wh + 32768;
    _Float16* h1h = Wh;                          // phase2: [64][256] swizzled
    _Float16* h1l = Wh + 16384;
    _Float16* W2h = Wh + 32768;                  // [128][128] swizzled
    _Float16* W2l = Wh + 49152;
    float*    mArr = (float*)(ldsraw + 131072);  // [128]

    const int tid = threadIdx.x;
    const int a0  = blockIdx.x * 64;
    const int l = tid & 63, wv = tid >> 6;
    const int row16 = l & 15, kgrp = l >> 4;
    const int at = wv & 3, chf = wv >> 2;

    {
        const uint4* ph = (const uint4*)planes;
        const uint4* pl = (const uint4*)(planes + 32768);
        uint4* dh = (uint4*)Wh; uint4* dl = (uint4*)Wl;
#pragma unroll
        for (int i = 0; i < 8; ++i) {
            int g = i * 512 + tid;
            int c = g >> 4, ch = g & 15;
            int sw = c * 16 + (ch ^ (c & 15));
            dh[sw] = ph[g]; dl[sw] = pl[g];
        }
    }

    v8h rh[4], rl[4];
    {
        const float* rb = r + (size_t)(a0 + at * 16 + row16) * FR + kgrp * 8;
#pragma unroll
        for (int ks = 0; ks < 4; ++ks) {
            float4 x0 = *(const float4*)(rb + ks * 32);
            float4 x1 = *(const float4*)(rb + ks * 32 + 4);
            float xs[8] = {x0.x, x0.y, x0.z, x0.w, x1.x, x1.y, x1.z, x1.w};
#pragma unroll
            for (int j = 0; j < 8; ++j) {
                _Float16 h = (_Float16)xs[j];
                rh[ks][j] = h;
                rl[ks][j] = (_Float16)((xs[j] - (float)h) * 4096.f);
            }
        }
    }
    __syncthreads();

    v4h hpack[8], lpack[8];
    {
#pragma unroll
        for (int ct = 0; ct < 8; ++ct) {
            int crow = chf * 128 + ct * 16 + row16;
            v4f a = {0.f, 0.f, 0.f, 0.f}, cr = {0.f, 0.f, 0.f, 0.f};
            int rbo = crow * 128, sw = crow & 15;
#pragma unroll
            for (int ks = 0; ks < 4; ++ks) {
                int off = rbo + (((ks * 4 + kgrp) ^ sw) * 8);
                v8h wh = *(const v8h*)(Wh + off);
                v8h wl = *(const v8h*)(Wl + off);
                a  = __builtin_amdgcn_mfma_f32_16x16x32_f16(wh, rh[ks], a,  0, 0, 0);
                cr = __builtin_amdgcn_mfma_f32_16x16x32_f16(wh, rl[ks], cr, 0, 0, 0);
                cr = __builtin_amdgcn_mfma_f32_16x16x32_f16(wl, rh[ks], cr, 0, 0, 0);
            }
            int colb = chf * 128 + ct * 16 + kgrp * 4;
            const float* bp = (colb < 128) ? (b1s + colb) : (b1e + (colb - 128));
            float4 bv = *(const float4*)bp;
            float bvx[4] = {bv.x, bv.y, bv.z, bv.w};
#pragma unroll
            for (int j = 0; j < 4; ++j) {
                float v = fast_tanh(a[j] + cr[j] * 2.44140625e-4f + bvx[j]);
                _Float16 h = (_Float16)v;
                hpack[ct][j] = h;
                lpack[ct][j] = (_Float16)((v - (float)h) * 4096.f);
            }
        }
    }
    __syncthreads();

    {
        int arow = at * 16 + row16;
#pragma unroll
        for (int ct = 0; ct < 8; ++ct) {
            int colb = chf * 128 + ct * 16 + kgrp * 4;
            int chs = (colb >> 3) ^ row16;
            int off = arow * 256 + chs * 8 + (colb & 7);
            *(v4h*)(h1h + off) = hpack[ct];
            *(v4h*)(h1l + off) = lpack[ct];
        }
        const uint4* ph = (const uint4*)(planes + 65536);
        const uint4* pl = (const uint4*)(planes + 81920);
        uint4* dh = (uint4*)W2h; uint4* dl = (uint4*)W2l;
#pragma unroll
        for (int i = 0; i < 4; ++i) {
            int g = i * 512 + tid;
            int c = g >> 4, ch = g & 15;
            int sw = c * 16 + (ch ^ (c & 15));
            dh[sw] = ph[g]; dl[sw] = pl[g];
        }
    }
    __syncthreads();

    {
        const int arow = at * 16 + row16;
        v8h bh[4], bl[4];
#pragma unroll
        for (int ks = 0; ks < 4; ++ks) {
            int chunk = chf * 16 + ks * 4 + kgrp;
            int off = arow * 256 + ((chunk ^ row16) * 8);
            bh[ks] = *(const v8h*)(h1h + off);
            bl[ks] = *(const v8h*)(h1l + off);
        }
        float ps = 0.f;
#pragma unroll
        for (int ct2 = 0; ct2 < 4; ++ct2) {
            int c2 = chf * 64 + ct2 * 16 + row16;
            v4f a = {0.f, 0.f, 0.f, 0.f}, cr = {0.f, 0.f, 0.f, 0.f};
            int rbo = c2 * 128, sw = c2 & 15;
#pragma unroll
            for (int ks = 0; ks < 4; ++ks) {
                int off = rbo + (((ks * 4 + kgrp) ^ sw) * 8);
                v8h wh = *(const v8h*)(W2h + off);
                v8h wl = *(const v8h*)(W2l + off);
                a  = __builtin_amdgcn_mfma_f32_16x16x32_f16(wh, bh[ks], a,  0, 0, 0);
                cr = __builtin_amdgcn_mfma_f32_16x16x32_f16(wh, bl[ks], cr, 0, 0, 0);
                cr = __builtin_amdgcn_mfma_f32_16x16x32_f16(wl, bh[ks], cr, 0, 0, 0);
            }
            int cb = ct2 * 16 + kgrp * 4;
            float4 b2v = *(const float4*)((chf ? b2e : b2s) + cb);
            float4 w3v = *(const float4*)((chf ? w3e : w3s) + cb);
            float b2x[4] = {b2v.x, b2v.y, b2v.z, b2v.w};
            float w3x[4] = {w3v.x, w3v.y, w3v.z, w3v.w};
#pragma unroll
            for (int j = 0; j < 4; ++j) {
                float h2 = fast_tanh(a[j] + cr[j] * 2.44140625e-4f + b2x[j]);
                ps = fmaf(h2, w3x[j], ps);
            }
        }
        ps += __shfl_xor(ps, 16);
        ps += __shfl_xor(ps, 32);
        if (l < 16) mArr[chf * 64 + at * 16 + l] = ps + (chf ? b3e[0] : b3s[0]);
    }
    __syncthreads();

    if (tid < 64) {
        int atom = a0 + tid;
        float ms = mArr[tid], me = mArr[64 + tid];
        float sg = fmaf(10.f * ms, ms, 4.f);            // sigma = 4 + 10 m^2
        float p  = sg * sqrtf(sg);                      // sigma^1.5
        float q  = 0.31622776601683794f * fabsf(me);    // sqrt(eps)
        __half2 pq = __halves2half2(__float2half(p), __float2half(q));
        atomd[atom] = make_float4(xyz[3 * atom], xyz[3 * atom + 1],
                                  xyz[3 * atom + 2], __builtin_bit_cast(float, pq));
    }
}

// ---------------- kernel 2: pair energies (round-6 LDS-staged version) ----------------
__device__ __forceinline__ float pair_e(const float4* atomd, int ia, int ib)
{
    float4 A = atomd[ia], B = atomd[ib];
    float dx = A.x - B.x, dy = A.y - B.y, dz = A.z - B.z;
    float D2 = fmaf(dx, dx, fmaf(dy, dy, dz * dz));
    float inv = __builtin_amdgcn_rcpf(D2);
    float inv3 = inv * inv * inv;
    __half2 ha = __builtin_bit_cast(__half2, A.w);
    __half2 hb = __builtin_bit_cast(__half2, B.w);
    float pp = __low2float(ha) * __low2float(hb);    // (sig_i*sig_j)^1.5
    float qq = __high2float(ha) * __high2float(hb);  // eps_mixed
    float s6 = pp * pp * inv3;                       // (sig_i*sig_j)^3 / D2^3
    return 4.f * qq * (s6 * s6 - s6);
}

__global__ __launch_bounds__(PT, 1) void k_pair(
    const float4* __restrict__ atomg, const int* __restrict__ pairs,
    const int* __restrict__ num_pairs,
    float* __restrict__ blocksums, int P)
{
    extern __shared__ char smem[];
    float4* atomd = (float4*)smem;                         // 8192 * 16B = 128 KiB
    int*    off   = (int*)(smem + NATOM * 16);             // 65 ints (+pad)
    float*  bsum  = (float*)(smem + NATOM * 16 + 68 * 4);  // 64 floats

    const int tid = threadIdx.x;

#pragma unroll
    for (int i = 0; i < NATOM / PT; ++i) atomd[i * PT + tid] = atomg[i * PT + tid];
    if (tid < 64) {
        int run = num_pairs[tid];
#pragma unroll
        for (int d = 1; d < 64; d <<= 1) {
            int o = __shfl_up(run, d);
            if (tid >= d) run += o;
        }
        off[tid + 1] = run;
        if (tid == 0) off[0] = 0;
        bsum[tid] = 0.f;
    }
    __syncthreads();

    const int base = (blockIdx.x * PT + tid) * PPT;
    const bool fast = (base + PPT <= P);

    if (__all(fast)) {
        int pr2[PPT * 2];
        const int4* pp4 = (const int4*)(pairs + (size_t)base * 2);
#pragma unroll
        for (int i = 0; i < PPT / 2; ++i) {
            int4 v = pp4[i];
            pr2[4*i] = v.x; pr2[4*i+1] = v.y; pr2[4*i+2] = v.z; pr2[4*i+3] = v.w;
        }
        int s = 0;
#pragma unroll
        for (int st = 32; st; st >>= 1) { int ns = s + st; if (ns <= NSEG - 1 && off[ns] <= base) s = ns; }
        float acc = 0.f;
        if (base + PPT <= off[s + 1] || s == NSEG - 1) {
#pragma unroll
            for (int i = 0; i < PPT; ++i)
                acc += pair_e(atomd, pr2[2 * i], pr2[2 * i + 1]);
        } else {
            int off_next = off[s + 1];
#pragma unroll
            for (int i = 0; i < PPT; ++i) {
                int idx = base + i;
                while (s < NSEG - 1 && idx >= off_next) {
                    if (acc != 0.f) atomicAdd(&bsum[s], acc);
                    acc = 0.f; ++s; off_next = off[s + 1];
                }
                acc += pair_e(atomd, pr2[2 * i], pr2[2 * i + 1]);
            }
        }
        int s0 = __builtin_amdgcn_readfirstlane(s);
        if (__all(s == s0)) {
            float v = acc;
#pragma unroll
            for (int o = 32; o; o >>= 1) v += __shfl_xor(v, o);
            if ((tid & 63) == 0) atomicAdd(&bsum[s0], v);
        } else {
            atomicAdd(&bsum[s], acc);
        }
    } else if (base < P) {
        int s = 0;
#pragma unroll
        for (int st = 32; st; st >>= 1) { int ns = s + st; if (ns <= NSEG - 1 && off[ns] <= base) s = ns; }
        int off_next = off[s + 1];
        float acc = 0.f;
        for (int i = 0; i < PPT; ++i) {
            int idx = base + i;
            if (idx >= P) break;
            while (s < NSEG - 1 && idx >= off_next) {
                if (acc != 0.f) atomicAdd(&bsum[s], acc);
                acc = 0.f; ++s; off_next = off[s + 1];
            }
            acc += pair_e(atomd, pairs[2 * (size_t)idx], pairs[2 * (size_t)idx + 1]);
        }
        if (acc != 0.f) atomicAdd(&bsum[s], acc);
    }
    __syncthreads();
    if (tid < NSEG) blocksums[blockIdx.x * NSEG + tid] = bsum[tid];
}

// ---------------- kernel 3: deterministic final reduce ----------------
__global__ __launch_bounds__(512) void k_reduce(const float* __restrict__ bs, float* __restrict__ out)
{
    __shared__ float red[8][NSEG];
    int b = threadIdx.x & 63, part = threadIdx.x >> 6;
    float s = 0.f;
    for (int j = part; j < PB; j += 8) s += bs[(size_t)j * NSEG + b];
    red[part][b] = s;
    __syncthreads();
    if (threadIdx.x < NSEG) {
        float t = 0.f;
#pragma unroll
        for (int p = 0; p < 8; ++p) t += red[p][threadIdx.x];
        out[threadIdx.x] = t;
    }
}

extern "C" void kernel_launch(void* const* d_in, const int* in_sizes, int n_in,
                              void* d_out, int out_size, void* d_ws, size_t ws_size,
                              hipStream_t stream)
{
    const float* r    = (const float*)d_in[0];
    const float* xyz  = (const float*)d_in[1];
    const int*   prs  = (const int*)d_in[2];
    const int*   np   = (const int*)d_in[3];
    const float* sW1  = (const float*)d_in[4];
    const float* sb1  = (const float*)d_in[5];
    const float* sW2  = (const float*)d_in[6];
    const float* sb2  = (const float*)d_in[7];
    const float* sW3  = (const float*)d_in[8];
    const float* sb3  = (const float*)d_in[9];
    const float* eW1  = (const float*)d_in[10];
    const float* eb1  = (const float*)d_in[11];
    const float* eW2  = (const float*)d_in[12];
    const float* eb2  = (const float*)d_in[13];
    const float* eW3  = (const float*)d_in[14];
    const float* eb3  = (const float*)d_in[15];
    float* out = (float*)d_out;
    const int P = in_sizes[2] / 2;

    _Float16* planes = (_Float16*)d_ws;                          // 98304 f16 = 192 KB
    float4*   atomd  = (float4*)((char*)d_ws + 196608);          // 8192 f4 = 128 KB
    float*    bsums  = (float*)((char*)d_ws + 196608 + 131072);  // PB*64 f32

    k_prep<<<96, 512, 0, stream>>>(sW1, eW1, sW2, eW2, planes);

    size_t smem1 = 131072 + 512;   // W/h1 regions + mArr
    hipFuncSetAttribute((const void*)k_mm, hipFuncAttributeMaxDynamicSharedMemorySize, (int)smem1);
    k_mm<<<NATOM / 64, 512, smem1, stream>>>(r, xyz, planes, sb1, eb1, sb2, eb2,
                                             sW3, eW3, sb3, eb3, atomd);

    size_t smem = (size_t)NATOM * 16 + 68 * 4 + NSEG * 4;   // 131,600 B
    hipFuncSetAttribute((const void*)k_pair, hipFuncAttributeMaxDynamicSharedMemorySize, (int)smem);
    k_pair<<<PB, PT, smem, stream>>>(atomd, prs, np, bsums, P);
    k_reduce<<<1, 512, 0, stream>>>(bsums, out);
}